// Round 9
// baseline (386.688 us; speedup 1.0000x reference)
//
#include <hip/hip_runtime.h>
#include <math.h>

#define BB 4096
#define LL 200
#define HH 32
#define PF 8      // prefetch ring depth (deeper pipe on 25-chunk stream)

// ---------------------------------------------------------------------------
// R12 = R11 resubmitted verbatim: the R11 bench died at the container level
// ("MI355X container failed twice") with no kernel verdict; mutating the
// kernel on zero data would confound the A/B vs R10. Levers under test:
//   1. PF 5->8: per-wave serial stall 25*lat/5 -> 25*lat/8.
//   2. __launch_bounds__(512,6): VGPR cap ~84 (PF8 ring ~32 + state ~35
//      fits), 24 waves/CU resident vs 16.
//   3. Stream preload hoisted ABOVE the wg/gt/c preamble (~300 cyc of
//      VALU+shfl hides the first loads' latency).
// R10 post-mortem: concurrency ledger complete -- 8.6/24/8/32 waves per CU
// across 3 load paths all land at 6-8 GB/s/CU read. Per-CU outstanding-
// miss (MSHR) ceiling x ~128B / loaded-latency fits every round; m13 copy
// READ side ~12 GB/s/CU (6.29 TB/s is R+W) => we're 1.5-1.7x off the
// pure-read wall, not 4x. The 800-MiB fills run unconditionally (harness
// reset) -- constant ~220 us of dur_us, not caused by d_ws use.
// If this round is flat: declare roofline (pattern ceiling ~2.2-2.5 TB/s).
// ---------------------------------------------------------------------------

template<int CTRL>
__device__ __forceinline__ float dpp_ror_add(float x)
{
    // dst = x + rotate_within_row16(x, CTRL); VALU-pipe only.
    int y = __builtin_amdgcn_update_dpp(0, __float_as_int(x),
                                        CTRL, 0xF, 0xF, true);
    return x + __int_as_float(y);
}

__global__ __launch_bounds__(512, 6) void actor_fused_kernel(
    const float* __restrict__ gs,
    const float* __restrict__ ls,
    const float* __restrict__ W_w, const float* __restrict__ W_b,
    const float* __restrict__ U_w, const float* __restrict__ U_b,
    const float* __restrict__ att_w, const float* __restrict__ att_b,
    const float* __restrict__ l1_w, const float* __restrict__ l1_b,
    const float* __restrict__ l2_w, const float* __restrict__ l2_b,
    const float* __restrict__ l3_w, const float* __restrict__ l3_b,
    float* __restrict__ out)
{
    __shared__ float c_lds[64];
    __shared__ __align__(16) float y_part[8][64];
    __shared__ float S_part[8];
    __shared__ __align__(16) float s_x [4 * 64];
    __shared__ __align__(16) float s_a1[4 * 260];  // pad 260: conflict-free
    __shared__ __align__(16) float s_a2[4 * 260];

    const int tid  = threadIdx.x;
    const int lane = tid & 63;
    const int wid  = tid >> 6;          // 0..7
    const int rblk = wid >> 1;          // row within block 0..3
    const int hpart= wid & 1;           // which 100-l half of the row
    const int b    = blockIdx.x * 4 + rblk;

    const int h    = lane & 31;   // owned hidden unit (both halves)
    const int half = lane >> 5;   // d-half for 64-d dots
    const int q    = lane & 15;   // d-quad within l-group

    // ---- stream preload FIRST: loads in flight under the whole preamble ----
    const float4* xs = (const float4*)(ls + (size_t)b * (LL * 64));
    const int c0 = hpart * 25;
    float4 Xbuf[PF];
    #pragma unroll
    for (int i = 0; i < PF; ++i)
        Xbuf[i] = xs[(c0 + i) * 64 + lane];

    // ================= Phase A preamble: attention pooling =================
    // (both waves of a pair compute identical wg/gt/s0 for their row)

    const float4* g4 = (const float4*)(gs + (size_t)b * 64);
    const float4* W4 = (const float4*)(W_w);
    float wg = (half == 0) ? W_b[h] : 0.f;
    #pragma unroll
    for (int dd = 0; dd < 8; ++dd) {
        float4 gv = g4[half * 8 + dd];
        float4 wv = W4[h * 16 + half * 8 + dd];
        wg += gv.x * wv.x + gv.y * wv.y + gv.z * wv.z + gv.w * wv.w;
    }
    wg += __shfl_xor(wg, 32);     // all lanes now hold wg[h]

    float gt = wg * att_w[h];
    float t2 = wg * att_w[HH + h];
    #pragma unroll
    for (int m = 1; m < 32; m <<= 1) {
        gt += __shfl_xor(gt, m);
        t2 += __shfl_xor(t2, m);
    }
    const float attb = att_b[0];
    const float lin0 = gt + t2 + attb;
    const float s0   = (lin0 > 0.f) ? lin0 : 0.01f * lin0;

    // ---- c[d] = sum_h a_l[h]*U_w[h][d] (b-independent; benign race) ----
    float c = 0.f;
    float ubal = 0.f;
    #pragma unroll
    for (int hh = 0; hh < HH; ++hh) {
        const float alh = att_w[HH + hh];        // uniform -> s_load
        c    += alh * U_w[hh * 64 + lane];       // coalesced, L1-hot
        ubal += alh * U_b[hh];
    }
    c_lds[lane] = c;              // all waves write identical values
    __syncthreads();
    const float4 cq = *(const float4*)&c_lds[4 * q];
    const float base = gt + ubal + attb;

    // ---- stream: this wave's 25 chunks (half a row), PF=8 ring ----
    float4 yx = make_float4(0.f, 0.f, 0.f, 0.f);
    float Sacc = 0.f;

    #pragma unroll                 // FULL unroll: ring index compile-time
    for (int t = 0; t < 25; ++t) {
        float4 X = Xbuf[t & (PF - 1)];
        if (t < 25 - PF)           // compile-time guard: clean tail
            Xbuf[t & (PF - 1)] = xs[(c0 + t + PF) * 64 + lane];

        float p = X.x * cq.x + X.y * cq.y + X.z * cq.z + X.w * cq.w;
        p = dpp_ror_add<0x121>(p);   // row_ror:1  } VALU-pipe 16-lane
        p = dpp_ror_add<0x122>(p);   // row_ror:2  } rotate-reduction
        p = dpp_ror_add<0x124>(p);   // row_ror:4  }
        p = dpp_ror_add<0x128>(p);   // row_ror:8  } group dot x[l].c
        const float linv = p + base;
        const float sl = (linv > 0.f) ? linv : 0.01f * linv;
        yx.x += sl * X.x;
        yx.y += sl * X.y;
        yx.z += sl * X.z;
        yx.w += sl * X.w;
        Sacc += sl;                // identical across the 16-lane group
    }

    // ---- combine the 4 l-groups within the wave ----
    #pragma unroll
    for (int m = 16; m < 64; m <<= 1) {
        yx.x += __shfl_xor(yx.x, m);
        yx.y += __shfl_xor(yx.y, m);
        yx.z += __shfl_xor(yx.z, m);
        yx.w += __shfl_xor(yx.w, m);
        Sacc += __shfl_xor(Sacc, m);
    }
    if (lane < 16) *(float4*)&y_part[wid][4 * q] = yx;
    if (lane == 0) S_part[wid] = Sacc;
    __syncthreads();

    // ---- even wave of each pair finalizes its row ----
    if (!hpart) {
        const float Stot = S_part[wid] + S_part[wid + 1];
        float V = (half == 0) ? (U_b[h] * Stot) : 0.f;
        const float4* U4  = (const float4*)U_w;
        const float4* ya4 = (const float4*)&y_part[wid][0];
        const float4* yb4 = (const float4*)&y_part[wid + 1][0];
        #pragma unroll
        for (int dd = 0; dd < 8; ++dd) {
            float4 uv = U4[h * 16 + half * 8 + dd];
            float4 va = ya4[half * 8 + dd];     // broadcast within half
            float4 vb = yb4[half * 8 + dd];
            V += uv.x * (va.x + vb.x) + uv.y * (va.y + vb.y)
               + uv.z * (va.z + vb.z) + uv.w * (va.w + vb.w);
        }
        V += __shfl_xor(V, 32);    // all lanes hold full V[h]

        const float total = s0 + Stot;
        const float n0    = s0 / total;
        const float outv  = (lane < 32) ? (n0 * wg) : (V / total);
        s_x[rblk * 64 + lane] = fmaxf(outv, 0.f);
    }
    __syncthreads();

    // ===== Phase B: MLP 64->256->256->8 (8 waves x 32 units, coalesced) =====
    const int kl  = lane & 15;
    const int lgb = lane >> 4;

    // ---- layer 1: 8 iters x 4 consecutive units; 1 KB contiguous loads ----
    {
        float4 xr[4];
        #pragma unroll
        for (int r = 0; r < 4; ++r)
            xr[r] = *(const float4*)&s_x[r * 64 + kl * 4];

        #pragma unroll
        for (int i = 0; i < 8; ++i) {
            const int u = (wid << 5) + (i << 2) + lgb;
            const float4 wv = *(const float4*)(l1_w + u * 64 + kl * 4);
            const float bias = l1_b[u];
            #pragma unroll
            for (int r = 0; r < 4; ++r) {
                float acc = wv.x * xr[r].x + wv.y * xr[r].y
                          + wv.z * xr[r].z + wv.w * xr[r].w;
                acc = dpp_ror_add<0x121>(acc);
                acc = dpp_ror_add<0x122>(acc);
                acc = dpp_ror_add<0x124>(acc);
                acc = dpp_ror_add<0x128>(acc);   // 16-lane sum
                if (kl == 0)
                    s_a1[r * 260 + u] = fmaxf(acc + bias, 0.f);
            }
        }
    }
    __syncthreads();

    // ---- layer 2: weights 4x256B contiguous; a1 from LDS (broadcast) ----
    {
        #pragma unroll
        for (int i = 0; i < 8; ++i) {
            const int u = (wid << 5) + (i << 2) + lgb;
            const float* wr = l2_w + (size_t)u * 256;
            const float4 wv0 = *(const float4*)(wr +   0 + kl * 4);
            const float4 wv1 = *(const float4*)(wr +  64 + kl * 4);
            const float4 wv2 = *(const float4*)(wr + 128 + kl * 4);
            const float4 wv3 = *(const float4*)(wr + 192 + kl * 4);
            const float bias = l2_b[u];
            #pragma unroll
            for (int r = 0; r < 4; ++r) {
                const float4 a0 = *(const float4*)&s_a1[r * 260 +   0 + kl * 4];
                const float4 a1 = *(const float4*)&s_a1[r * 260 +  64 + kl * 4];
                const float4 a2 = *(const float4*)&s_a1[r * 260 + 128 + kl * 4];
                const float4 a3 = *(const float4*)&s_a1[r * 260 + 192 + kl * 4];
                float acc = wv0.x * a0.x + wv0.y * a0.y + wv0.z * a0.z + wv0.w * a0.w;
                acc      += wv1.x * a1.x + wv1.y * a1.y + wv1.z * a1.z + wv1.w * a1.w;
                acc      += wv2.x * a2.x + wv2.y * a2.y + wv2.z * a2.z + wv2.w * a2.w;
                acc      += wv3.x * a3.x + wv3.y * a3.y + wv3.z * a3.z + wv3.w * a3.w;
                acc = dpp_ror_add<0x121>(acc);
                acc = dpp_ror_add<0x122>(acc);
                acc = dpp_ror_add<0x124>(acc);
                acc = dpp_ror_add<0x128>(acc);   // 16-lane sum
                if (kl == 0)
                    s_a2[r * 260 + u] = fmaxf(acc + bias, 0.f);
            }
        }
    }
    __syncthreads();

    // ---- layer 3 + sigmoid: threads 0..31, float4 LDS reads (tiny) ----
    if (tid < 32) {
        int r = tid >> 3, o = tid & 7;
        float acc = l3_b[o];
        const float4* wr4 = (const float4*)(l3_w + o * 256);
        const float4* a4  = (const float4*)&s_a2[r * 260];
        #pragma unroll 8
        for (int k = 0; k < 64; ++k) {
            float4 av = a4[k];
            float4 wv = wr4[k];
            acc += av.x * wv.x + av.y * wv.y + av.z * wv.z + av.w * wv.w;
        }
        out[(size_t)(blockIdx.x * 4 + r) * 8 + o] =
            1.f / (1.f + __expf(-acc));   // MAX_ACTION = 1
    }
}

// ---------------------------------------------------------------------------
extern "C" void kernel_launch(void* const* d_in, const int* in_sizes, int n_in,
                              void* d_out, int out_size, void* d_ws, size_t ws_size,
                              hipStream_t stream)
{
    const float* gs    = (const float*)d_in[0];
    const float* ls    = (const float*)d_in[1];
    const float* W_w   = (const float*)d_in[2];
    const float* W_b   = (const float*)d_in[3];
    const float* U_w   = (const float*)d_in[4];
    const float* U_b   = (const float*)d_in[5];
    const float* att_w = (const float*)d_in[6];
    const float* att_b = (const float*)d_in[7];
    const float* l1_w  = (const float*)d_in[8];
    const float* l1_b  = (const float*)d_in[9];
    const float* l2_w  = (const float*)d_in[10];
    const float* l2_b  = (const float*)d_in[11];
    const float* l3_w  = (const float*)d_in[12];
    const float* l3_b  = (const float*)d_in[13];

    actor_fused_kernel<<<BB / 4, 512, 0, stream>>>(
        gs, ls, W_w, W_b, U_w, U_b, att_w, att_b,
        l1_w, l1_b, l2_w, l2_b, l3_w, l3_b, (float*)d_out);
}